// Round 3
// baseline (654.564 us; speedup 1.0000x reference)
//
#include <hip/hip_runtime.h>
#include <math.h>

#define EPS 1e-10f
#define COS_EPS 1e-8f

// Shapes: img (256,4,3,112,112) fp32; feat (256,4,512); feat_norm (256,4,1)
// Per frame: 3*112*112 = 37632 floats = 9408 float4.
#define NB 256
#define NF 4
#define FRAME_F4 9408     // float4 per frame
#define BLK_PER_B 37      // 37*256 = 9472 >= 9408

// Workspace layout (all zeroed by one 7176-B memset):
//   float ws_sq[768]   squared-diff sums per (b,pair), atomic-accumulated
//   int   ws_neq[768]  any-neq flags (vs frame 0), atomic-OR
//   int   cnt[256]     blocks-done counter per batch
//   int   cnt_g        batches-done counter
//   float ws_loss      loss accumulator

__global__ __launch_bounds__(256) void fused(const float* __restrict__ img,
                                             const float* __restrict__ feat,
                                             const float* __restrict__ feat_norm,
                                             float* __restrict__ ws_sq,
                                             int* __restrict__ ws_neq,
                                             int* __restrict__ cnt,
                                             int* __restrict__ cnt_g,
                                             float* __restrict__ ws_loss,
                                             float* __restrict__ out) {
    const int b   = blockIdx.y;
    const int bx  = blockIdx.x;
    const int tid = threadIdx.x;
    const int idx = bx * 256 + tid;

    // ---- stage 1: img squared-diff + neq partials ----
    float s1 = 0.f, s2 = 0.f, s3 = 0.f;
    int   n1 = 0,   n2 = 0,   n3 = 0;

    if (idx < FRAME_F4) {
        const float4* base = (const float4*)img + (size_t)b * NF * FRAME_F4;
        float4 f0 = base[idx];
        float4 f1 = base[FRAME_F4 + idx];
        float4 f2 = base[2 * FRAME_F4 + idx];
        float4 f3 = base[3 * FRAME_F4 + idx];

        float dx, dy, dz, dw;
        dx = f1.x - f0.x; dy = f1.y - f0.y; dz = f1.z - f0.z; dw = f1.w - f0.w;
        s1 = dx*dx + dy*dy + dz*dz + dw*dw;
        dx = f2.x - f1.x; dy = f2.y - f1.y; dz = f2.z - f1.z; dw = f2.w - f1.w;
        s2 = dx*dx + dy*dy + dz*dz + dw*dw;
        dx = f3.x - f2.x; dy = f3.y - f2.y; dz = f3.z - f2.z; dw = f3.w - f2.w;
        s3 = dx*dx + dy*dy + dz*dz + dw*dw;

        n1 = (f1.x != f0.x) | (f1.y != f0.y) | (f1.z != f0.z) | (f1.w != f0.w);
        n2 = (f2.x != f0.x) | (f2.y != f0.y) | (f2.z != f0.z) | (f2.w != f0.w);
        n3 = (f3.x != f0.x) | (f3.y != f0.y) | (f3.z != f0.z) | (f3.w != f0.w);
    }

    for (int off = 32; off > 0; off >>= 1) {
        s1 += __shfl_down(s1, off);
        s2 += __shfl_down(s2, off);
        s3 += __shfl_down(s3, off);
        n1 |= __shfl_down(n1, off);
        n2 |= __shfl_down(n2, off);
        n3 |= __shfl_down(n3, off);
    }

    __shared__ float ls[3][4];
    __shared__ int   ln[3][4];
    __shared__ bool  is_last;
    const int wave = tid >> 6;
    if ((tid & 63) == 0) {
        ls[0][wave] = s1; ls[1][wave] = s2; ls[2][wave] = s3;
        ln[0][wave] = n1; ln[1][wave] = n2; ln[2][wave] = n3;
    }
    __syncthreads();
    if (tid == 0) {
        const int base3 = b * 3;
        atomicAdd(&ws_sq[base3 + 0], ls[0][0] + ls[0][1] + ls[0][2] + ls[0][3]);
        atomicAdd(&ws_sq[base3 + 1], ls[1][0] + ls[1][1] + ls[1][2] + ls[1][3]);
        atomicAdd(&ws_sq[base3 + 2], ls[2][0] + ls[2][1] + ls[2][2] + ls[2][3]);
        int m1 = ln[0][0] | ln[0][1] | ln[0][2] | ln[0][3];
        int m2 = ln[1][0] | ln[1][1] | ln[1][2] | ln[1][3];
        int m3 = ln[2][0] | ln[2][1] | ln[2][2] | ln[2][3];
        if (m1) atomicOr(&ws_neq[base3 + 0], 1);
        if (m2) atomicOr(&ws_neq[base3 + 1], 1);
        if (m3) atomicOr(&ws_neq[base3 + 2], 1);
        __threadfence();                       // order partial-adds before counter bump
        int old = atomicAdd(&cnt[b], 1);
        is_last = (old == BLK_PER_B - 1);
    }
    __syncthreads();
    if (!is_last) return;

    // ---- stage 2: this is the last block for batch b — finalize it ----
    const int p    = tid >> 6;      // wave id 0..3; waves 0..2 handle pairs
    const int lane = tid & 63;

    __shared__ float sh_term[3];
    if (p < 3) {
        // feat row = 512 floats = 128 float4
        const float4* fa = (const float4*)feat + ((size_t)b * NF + p) * 128;
        const float4* fb = fa + 128;

        float dab = 0.f, daa = 0.f, dbb = 0.f;
#pragma unroll
        for (int j = 0; j < 2; ++j) {
            float4 a  = fa[lane + 64 * j];
            float4 bb = fb[lane + 64 * j];
            dab += a.x * bb.x + a.y * bb.y + a.z * bb.z + a.w * bb.w;
            daa += a.x * a.x + a.y * a.y + a.z * a.z + a.w * a.w;
            dbb += bb.x * bb.x + bb.y * bb.y + bb.z * bb.z + bb.w * bb.w;
        }
        for (int off = 32; off > 0; off >>= 1) {
            dab += __shfl_down(dab, off);
            daa += __shfl_down(daa, off);
            dbb += __shfl_down(dbb, off);
        }
        if (lane == 0) {
            // coherent device-scope reads of the accumulated partials
            float sq = atomicAdd(&ws_sq[b * 3 + p], 0.0f);
            int   nq = atomicOr(&ws_neq[b * 3 + p], 0);
            float na   = fmaxf(sqrtf(daa), COS_EPS);
            float nb   = fmaxf(sqrtf(dbb), COS_EPS);
            float cosv = dab / (na * nb);
            float img_diff = sqrtf(sq) + EPS;
            float ratio = (1.0f - cosv) / img_diff;   // LIP = 0
            float term  = fmaxf(ratio, 0.0f);         // SQUARED = False
            float fn0   = feat_norm[b * NF];          // feat_norm[b,0,0]
            float w     = 1.0f / (expf(fn0) + EPS);
            bool  cond  = fn0 > 0.0f;                 // fn0 > -TAO, TAO = 0
            sh_term[p]  = (cond && nq) ? term * w : 0.0f;
        }
    }
    __syncthreads();
    if (tid == 0) {
        float fn0 = feat_norm[b * NF];
        float w   = 1.0f / (expf(fn0) + EPS);
        out[1 + b] = (fn0 > 0.0f) ? w : 0.0f;
        float pen = sh_term[0] + sh_term[1] + sh_term[2];
        atomicAdd(ws_loss, pen);
        __threadfence();
        int oldg = atomicAdd(cnt_g, 1);
        if (oldg == NB - 1) {
            // all 256 batch penalties are in; coherent read and write the mean
            float total = atomicAdd(ws_loss, 0.0f);
            out[0] = total * (1.0f / 256.0f);         // LAMB_LIP = 1
        }
    }
}

extern "C" void kernel_launch(void* const* d_in, const int* in_sizes, int n_in,
                              void* d_out, int out_size, void* d_ws, size_t ws_size,
                              hipStream_t stream) {
    const float* img       = (const float*)d_in[0];
    const float* feat      = (const float*)d_in[1];
    const float* feat_norm = (const float*)d_in[2];
    float* out = (float*)d_out;

    char* ws = (char*)d_ws;
    float* ws_sq   = (float*)ws;                    // 768 floats
    int*   ws_neq  = (int*)(ws + 768 * 4);          // 768 ints
    int*   cnt     = (int*)(ws + 1536 * 4);         // 256 ints
    int*   cnt_g   = (int*)(ws + 1792 * 4);         // 1 int
    float* ws_loss = (float*)(ws + 1793 * 4);       // 1 float

    hipMemsetAsync(d_ws, 0, 1794 * 4, stream);      // zero all accumulators/counters
    fused<<<dim3(BLK_PER_B, NB), 256, 0, stream>>>(img, feat, feat_norm,
                                                   ws_sq, ws_neq, cnt, cnt_g,
                                                   ws_loss, out);
}

// Round 4
// 221.752 us; speedup vs baseline: 2.9518x; 2.9518x over previous
//
#include <hip/hip_runtime.h>
#include <math.h>

#define EPS 1e-10f
#define COS_EPS 1e-8f

// Shapes: img (256,4,3,112,112) fp32; feat (256,4,512); feat_norm (256,4,1)
// Per frame: 3*112*112 = 37632 floats = 9408 float4.
#define NB 256
#define NF 4
#define FRAME_F4 9408     // float4 per frame

// One block per batch (256 blocks = 1 per CU), 1024 threads = 16 waves.
// Block streams its batch's 588 KB of img once, reduces in-block (no cross-
// block traffic, no fences), then computes the 3 feat cosines and outputs.
// out[0] zeroed by a 4-byte hipMemsetAsync; accumulated via one atomicAdd/block.
__global__ __launch_bounds__(1024) void fused(const float* __restrict__ img,
                                              const float* __restrict__ feat,
                                              const float* __restrict__ feat_norm,
                                              float* __restrict__ out) {
    const int b   = blockIdx.x;
    const int tid = threadIdx.x;

    // ---- stage 1: img squared-diff + neq, grid-stride within the batch ----
    const float4* base = (const float4*)img + (size_t)b * NF * FRAME_F4;

    float s1 = 0.f, s2 = 0.f, s3 = 0.f;
    int   n1 = 0,   n2 = 0,   n3 = 0;

    for (int idx = tid; idx < FRAME_F4; idx += 1024) {
        float4 f0 = base[idx];
        float4 f1 = base[FRAME_F4 + idx];
        float4 f2 = base[2 * FRAME_F4 + idx];
        float4 f3 = base[3 * FRAME_F4 + idx];

        float dx, dy, dz, dw;
        dx = f1.x - f0.x; dy = f1.y - f0.y; dz = f1.z - f0.z; dw = f1.w - f0.w;
        s1 += dx*dx + dy*dy + dz*dz + dw*dw;
        dx = f2.x - f1.x; dy = f2.y - f1.y; dz = f2.z - f1.z; dw = f2.w - f1.w;
        s2 += dx*dx + dy*dy + dz*dz + dw*dw;
        dx = f3.x - f2.x; dy = f3.y - f2.y; dz = f3.z - f2.z; dw = f3.w - f2.w;
        s3 += dx*dx + dy*dy + dz*dz + dw*dw;

        n1 |= (f1.x != f0.x) | (f1.y != f0.y) | (f1.z != f0.z) | (f1.w != f0.w);
        n2 |= (f2.x != f0.x) | (f2.y != f0.y) | (f2.z != f0.z) | (f2.w != f0.w);
        n3 |= (f3.x != f0.x) | (f3.y != f0.y) | (f3.z != f0.z) | (f3.w != f0.w);
    }

    // wave(64) reduction
    for (int off = 32; off > 0; off >>= 1) {
        s1 += __shfl_down(s1, off);
        s2 += __shfl_down(s2, off);
        s3 += __shfl_down(s3, off);
        n1 |= __shfl_down(n1, off);
        n2 |= __shfl_down(n2, off);
        n3 |= __shfl_down(n3, off);
    }

    __shared__ float ls[3][16];
    __shared__ int   ln[3][16];
    const int wave = tid >> 6;
    const int lane = tid & 63;
    if (lane == 0) {
        ls[0][wave] = s1; ls[1][wave] = s2; ls[2][wave] = s3;
        ln[0][wave] = n1; ln[1][wave] = n2; ln[2][wave] = n3;
    }
    __syncthreads();

    // ---- stage 2: waves 0..2 finalize pair p = wave id ----
    const int p = wave;
    __shared__ float sh_term[3];
    if (p < 3) {
        float sq = (lane < 16) ? ls[p][lane] : 0.0f;
        int   nq = (lane < 16) ? ln[p][lane] : 0;

        // feat row = 512 floats = 128 float4; 2 float4 per lane
        const float4* fa = (const float4*)feat + ((size_t)b * NF + p) * 128;
        const float4* fb = fa + 128;

        float dab = 0.f, daa = 0.f, dbb = 0.f;
#pragma unroll
        for (int j = 0; j < 2; ++j) {
            float4 a  = fa[lane + 64 * j];
            float4 bb = fb[lane + 64 * j];
            dab += a.x * bb.x + a.y * bb.y + a.z * bb.z + a.w * bb.w;
            daa += a.x * a.x + a.y * a.y + a.z * a.z + a.w * a.w;
            dbb += bb.x * bb.x + bb.y * bb.y + bb.z * bb.z + bb.w * bb.w;
        }
        for (int off = 32; off > 0; off >>= 1) {
            dab += __shfl_down(dab, off);
            daa += __shfl_down(daa, off);
            dbb += __shfl_down(dbb, off);
            sq  += __shfl_down(sq, off);
            nq  |= __shfl_down(nq, off);
        }

        if (lane == 0) {
            float na   = fmaxf(sqrtf(daa), COS_EPS);
            float nb   = fmaxf(sqrtf(dbb), COS_EPS);
            float cosv = dab / (na * nb);
            float img_diff = sqrtf(sq) + EPS;
            float ratio = (1.0f - cosv) / img_diff;   // LIP = 0
            float term  = fmaxf(ratio, 0.0f);         // SQUARED = False
            float fn0   = feat_norm[b * NF];          // feat_norm[b,0,0]
            float w     = 1.0f / (expf(fn0) + EPS);
            bool  cond  = fn0 > 0.0f;                 // fn0 > -TAO, TAO = 0
            sh_term[p]  = (cond && nq) ? term * w : 0.0f;
        }
    }
    __syncthreads();
    if (tid == 0) {
        float fn0 = feat_norm[b * NF];
        float w   = 1.0f / (expf(fn0) + EPS);
        out[1 + b] = (fn0 > 0.0f) ? w : 0.0f;
        float pen = sh_term[0] + sh_term[1] + sh_term[2];
        atomicAdd(&out[0], pen * (1.0f / 256.0f));    // LAMB_LIP = 1, mean
    }
}

extern "C" void kernel_launch(void* const* d_in, const int* in_sizes, int n_in,
                              void* d_out, int out_size, void* d_ws, size_t ws_size,
                              hipStream_t stream) {
    const float* img       = (const float*)d_in[0];
    const float* feat      = (const float*)d_in[1];
    const float* feat_norm = (const float*)d_in[2];
    float* out = (float*)d_out;

    hipMemsetAsync(out, 0, sizeof(float), stream);    // zero the loss accumulator
    fused<<<NB, 1024, 0, stream>>>(img, feat, feat_norm, out);
}